// Round 1
// baseline (190.221 us; speedup 1.0000x reference)
//
#include <hip/hip_runtime.h>
#include <hip/hip_bf16.h>
#include <stdint.h>

// Problem constants
#define B_  4
#define S_  1024
#define D_  1024
#define H_  16
#define HD_ 64

using f32x4  = __attribute__((ext_vector_type(4))) float;
using bf16x8 = __attribute__((ext_vector_type(8))) __bf16;
using bf16x4 = __attribute__((ext_vector_type(4))) __bf16;
using f32x4v = __attribute__((ext_vector_type(4))) float;

// ---------------------------------------------------------------------------
// global -> LDS direct load, 16B per lane. LDS dest must be wave-uniform base;
// HW writes lane i at base + i*16 (m104). Casts via integer detour (generic
// LDS ptr low 32 bits == LDS offset on gfx9+).
__device__ __forceinline__ void g2l16(const void* g, void* l) {
  using gp = const __attribute__((address_space(1))) unsigned int*;
  using lp = __attribute__((address_space(3))) unsigned int*;
  __builtin_amdgcn_global_load_lds((gp)(unsigned long long)g,
                                   (lp)(unsigned int)(unsigned long long)l,
                                   16, 0, 0);
}

// ---------------------------------------------------------------------------
// f32 -> bf16 conversion (vectorized, 4 elems/thread)
__global__ __launch_bounds__(256) void cvt_kernel(const float* __restrict__ in,
                                                  __bf16* __restrict__ out, int n) {
  int i = (blockIdx.x * 256 + threadIdx.x) * 4;
  if (i + 3 >= n) {
    if (i >= n) return;
    for (int k = 0; k < 4 && i + k < n; ++k) out[i + k] = (__bf16)in[i + k];
    return;
  }
  f32x4v v = *(const f32x4v*)(in + i);
  bf16x4 o;
  o[0] = (__bf16)v[0]; o[1] = (__bf16)v[1]; o[2] = (__bf16)v[2]; o[3] = (__bf16)v[3];
  *(bf16x4*)(out + i) = o;
}

// num_masked per batch (mask is all-false in the test; read bytewise)
__global__ __launch_bounds__(64) void nm_kernel(const unsigned char* __restrict__ m,
                                                int* __restrict__ nm) {
  int b = blockIdx.x, t = threadIdx.x;
  int s = 0;
  for (int i = t; i < S_; i += 64) s += (m[b * S_ + i] != 0) ? 1 : 0;
  #pragma unroll
  for (int k = 1; k < 64; k <<= 1) s += __shfl_xor(s, k);
  if (t == 0) nm[b] = s;
}

// ---------------------------------------------------------------------------
// NT GEMM: C[M,N] = A[M,K] * B[N,K]^T, bf16 in, f32 acc. m97 structure:
// 128x128 tile, BK=32, 256 thr = 4 waves (2x2, each 64x64 = 4x4 frags),
// global_load_lds width 16, mfma_f32_16x16x32_bf16.
template <bool OUT_BF16>
__global__ __launch_bounds__(256)
void gemm_nt(const __bf16* __restrict__ A, const __bf16* __restrict__ Bm,
             void* __restrict__ Cv, int N, int K) {
  __shared__ __bf16 sA[128 * 32];
  __shared__ __bf16 sB[128 * 32];
  const int tid = threadIdx.x;
  const int wv = tid >> 6, lane = tid & 63;
  const int row0 = blockIdx.y * 128, col0 = blockIdx.x * 128;
  const int wm = wv >> 1, wn = wv & 1;
  const int c0 = wv * 2, c1 = c0 + 1;
  const int srow = lane >> 2;            // row within 16-row chunk
  const int scol = (lane & 3) * 8;       // elem col (8 bf16 = 16B)
  const __bf16* Ab = A + (size_t)(row0 + srow) * K + scol;
  const __bf16* Bb = Bm + (size_t)(col0 + srow) * K + scol;
  const int fr = lane & 15, fk = (lane >> 4) * 8;

  f32x4 acc[4][4] = {};

  for (int k0 = 0; k0 < K; k0 += 32) {
    g2l16(Ab + (size_t)(c0 * 16) * K + k0, &sA[c0 * 512]);
    g2l16(Ab + (size_t)(c1 * 16) * K + k0, &sA[c1 * 512]);
    g2l16(Bb + (size_t)(c0 * 16) * K + k0, &sB[c0 * 512]);
    g2l16(Bb + (size_t)(c1 * 16) * K + k0, &sB[c1 * 512]);
    __syncthreads();   // drains vmcnt for global_load_lds

    bf16x8 af[4], bfr[4];
    #pragma unroll
    for (int m = 0; m < 4; ++m)
      af[m] = *(const bf16x8*)&sA[(wm * 64 + m * 16 + fr) * 32 + fk];
    #pragma unroll
    for (int n = 0; n < 4; ++n)
      bfr[n] = *(const bf16x8*)&sB[(wn * 64 + n * 16 + fr) * 32 + fk];

    #pragma unroll
    for (int m = 0; m < 4; ++m)
      #pragma unroll
      for (int n = 0; n < 4; ++n)
        acc[m][n] = __builtin_amdgcn_mfma_f32_16x16x32_bf16(af[m], bfr[n], acc[m][n], 0, 0, 0);

    __syncthreads();
  }

  const int g4 = (lane >> 4) * 4;
  if (OUT_BF16) {
    __bf16* C = (__bf16*)Cv;
    #pragma unroll
    for (int m = 0; m < 4; ++m)
      #pragma unroll
      for (int n = 0; n < 4; ++n)
        #pragma unroll
        for (int r = 0; r < 4; ++r)
          C[(size_t)(row0 + wm * 64 + m * 16 + g4 + r) * N + col0 + wn * 64 + n * 16 + fr] =
              (__bf16)acc[m][n][r];
  } else {
    float* C = (float*)Cv;
    #pragma unroll
    for (int m = 0; m < 4; ++m)
      #pragma unroll
      for (int n = 0; n < 4; ++n)
        #pragma unroll
        for (int r = 0; r < 4; ++r)
          C[(size_t)(row0 + wm * 64 + m * 16 + g4 + r) * N + col0 + wn * 64 + n * 16 + fr] =
              acc[m][n][r];
  }
}

// ---------------------------------------------------------------------------
// RoPE + RMSNorm + q per-dim scale. Block = one (b,s). Threads 0..127: Q,
// 128..255: K. Each thread owns 8 contiguous dims of one head (bf16x8 load).
// Rotate pairs (d, d+32) exchanged via __shfl_xor(.,4); RMS reduce over the
// 8-thread head group via __shfl_xor 1/2/4.
__global__ __launch_bounds__(256)
void rope_rms(const __bf16* __restrict__ QKV, __bf16* __restrict__ Qr,
              __bf16* __restrict__ Kr, const float* __restrict__ qsc,
              const float* __restrict__ ksc, const float* __restrict__ pds,
              const int* __restrict__ nm) {
  const int bs = blockIdx.x;
  const int b = bs >> 10, s = bs & 1023;
  const int t = threadIdx.x;
  const bool isK = t >= 128;
  const int t2 = t & 127;
  const int h = t2 >> 3, j = t2 & 7;

  const __bf16* src = QKV + (size_t)bs * 3072 + (isK ? 1024 : 0) + h * 64 + j * 8;
  bf16x8 xv = *(const bf16x8*)src;
  float f[8], of[8];
  #pragma unroll
  for (int i = 0; i < 8; ++i) f[i] = (float)xv[i];

  const float pos = (float)s - (float)nm[b];
  #pragma unroll
  for (int i = 0; i < 8; ++i) {
    const float other = __shfl_xor(f[i], 4);
    const float frc = (float)((j & 3) * 8 + i) * (1.0f / 32.0f);
    const float ang = pos * exp2f(frc * -13.287712379549449f); // 1/10000^frc
    float sn, cs;
    sincosf(ang, &sn, &cs);
    of[i] = (j & 4) ? (f[i] * cs + other * sn)   // second half: x2*cos + x1*sin
                    : (f[i] * cs - other * sn);  // first half:  x1*cos - x2*sin
  }

  float ss = 0.f;
  #pragma unroll
  for (int i = 0; i < 8; ++i) ss += of[i] * of[i];
  ss += __shfl_xor(ss, 1);
  ss += __shfl_xor(ss, 2);
  ss += __shfl_xor(ss, 4);
  const float rn = rsqrtf(ss * (1.0f / 64.0f) + 1e-6f);

  const float* sc = isK ? ksc : qsc;
  bf16x8 ov;
  #pragma unroll
  for (int i = 0; i < 8; ++i) {
    const int d = j * 8 + i;
    float v = of[i] * rn * sc[d];
    if (!isK) v *= 0.18033688011112042f * log1pf(expf(pds[d])); // LOG2E/8 * softplus
    ov[i] = (__bf16)v;
  }
  __bf16* dst = (isK ? Kr : Qr) + ((size_t)(b * H_ + h) * S_ + s) * HD_ + j * 8;
  *(bf16x8*)dst = ov;
}

// ---------------------------------------------------------------------------
// V transpose: QKV[:, 2048 + h*64 + d] -> Vt[b][h][d][s], 64x64 tiles via LDS.
__global__ __launch_bounds__(256)
void vtrans(const __bf16* __restrict__ QKV, __bf16* __restrict__ Vt) {
  const int st = blockIdx.x, h = blockIdx.y, b = blockIdx.z;
  __shared__ __bf16 tile[64][72];
  const int t = threadIdx.x;
  const int r = t >> 2, q = t & 3;

  const __bf16* src = QKV + (size_t)(b * S_ + st * 64 + r) * 3072 + 2048 + h * 64 + q * 16;
  bf16x8 v0 = *(const bf16x8*)src;
  bf16x8 v1 = *(const bf16x8*)(src + 8);
  *(bf16x8*)&tile[r][q * 16] = v0;
  *(bf16x8*)&tile[r][q * 16 + 8] = v1;
  __syncthreads();

  __bf16 outv[16];
  #pragma unroll
  for (int i = 0; i < 16; ++i) outv[i] = tile[q * 16 + i][r];
  __bf16* dst = Vt + ((size_t)(b * H_ + h) * HD_ + r) * S_ + st * 64 + q * 16;
  *(bf16x8*)dst = *(bf16x8*)&outv[0];
  *(bf16x8*)(dst + 8) = *(bf16x8*)&outv[8];
}

// ---------------------------------------------------------------------------
// Flash attention: block = (128 q rows, one (b,h)). 4 waves x 32 rows.
// K/V 64x64 tiles staged via global_load_lds with XOR swizzle (linear LDS
// dest + pre-swizzled global src; reads apply the same XOR) to avoid the
// 16-way bank conflict of a 128B-stride row-major tile.
__global__ __launch_bounds__(256)
void attn_fwd(const __bf16* __restrict__ Qr, const __bf16* __restrict__ Kr,
              const __bf16* __restrict__ Vt, __bf16* __restrict__ Ob,
              const int* __restrict__ nm) {
  const int q0 = blockIdx.x * 128;
  const int h = blockIdx.y, b = blockIdx.z;
  const int tid = threadIdx.x, wv = tid >> 6, lane = tid & 63;

  __shared__ __bf16 sK[64 * 64];
  __shared__ __bf16 sV[64 * 64];
  __shared__ __bf16 sP[4][32][72];

  const size_t bh = (size_t)(b * H_ + h);
  const __bf16* Qh = Qr + bh * (S_ * HD_);
  const __bf16* Kh = Kr + bh * (S_ * HD_);
  const __bf16* Vh = Vt + bh * (HD_ * S_);

  const int fr = lane & 15, g = lane >> 4;
  const int qbase = q0 + wv * 32;

  // Q fragments held in registers for the whole block
  bf16x8 qf[2][2];
  #pragma unroll
  for (int m = 0; m < 2; ++m)
    #pragma unroll
    for (int ks = 0; ks < 2; ++ks)
      qf[m][ks] = *(const bf16x8*)&Qh[(size_t)(qbase + m * 16 + fr) * HD_ + ks * 32 + g * 8];

  f32x4 oacc[2][4] = {};
  float mrun[2][4], lrun[2][4];
  #pragma unroll
  for (int m = 0; m < 2; ++m)
    #pragma unroll
    for (int r = 0; r < 4; ++r) { mrun[m][r] = -3e38f; lrun[m][r] = 0.f; }

  const int nmb = nm[b];
  const int srow = lane >> 3;                  // row within 8-row chunk
  const int ssw = ((lane & 7) ^ srow) * 8;     // inverse-swizzled source col
  const int c0 = wv * 2, c1 = c0 + 1;

  for (int kv0 = 0; kv0 < q0 + 128; kv0 += 64) {
    g2l16(&Kh[(size_t)(kv0 + c0 * 8 + srow) * HD_ + ssw], &sK[c0 * 512]);
    g2l16(&Kh[(size_t)(kv0 + c1 * 8 + srow) * HD_ + ssw], &sK[c1 * 512]);
    g2l16(&Vh[(size_t)(c0 * 8 + srow) * S_ + kv0 + ssw], &sV[c0 * 512]);
    g2l16(&Vh[(size_t)(c1 * 8 + srow) * S_ + kv0 + ssw], &sV[c1 * 512]);
    __syncthreads();

    // S = Q K^T  (rows q, cols kv)
    f32x4 sacc[2][4] = {};
    #pragma unroll
    for (int n = 0; n < 4; ++n) {
      const int krow = n * 16 + fr;
      #pragma unroll
      for (int ks = 0; ks < 2; ++ks) {
        bf16x8 kf = *(const bf16x8*)&sK[krow * 64 + ((ks * 32 + g * 8) ^ ((krow & 7) * 8))];
        #pragma unroll
        for (int m = 0; m < 2; ++m)
          sacc[m][n] = __builtin_amdgcn_mfma_f32_16x16x32_bf16(qf[m][ks], kf, sacc[m][n], 0, 0, 0);
      }
    }

    // mask: valid iff q >= kv && kv >= nm
    const bool fullv = (qbase >= kv0 + 63) && (kv0 >= nmb);
    if (!fullv) {
      #pragma unroll
      for (int m = 0; m < 2; ++m)
        #pragma unroll
        for (int n = 0; n < 4; ++n) {
          const int kv = kv0 + n * 16 + fr;
          #pragma unroll
          for (int r = 0; r < 4; ++r) {
            const int q = qbase + m * 16 + g * 4 + r;
            if (q < kv || kv < nmb) sacc[m][n][r] = -1e30f;
          }
        }
    }

    // online softmax (rows lane-parallel; 16-lane group reduces)
    #pragma unroll
    for (int m = 0; m < 2; ++m)
      #pragma unroll
      for (int r = 0; r < 4; ++r) {
        float mx = fmaxf(fmaxf(sacc[m][0][r], sacc[m][1][r]),
                         fmaxf(sacc[m][2][r], sacc[m][3][r]));
        mx = fmaxf(mx, __shfl_xor(mx, 1));
        mx = fmaxf(mx, __shfl_xor(mx, 2));
        mx = fmaxf(mx, __shfl_xor(mx, 4));
        mx = fmaxf(mx, __shfl_xor(mx, 8));
        const float mnew = fmaxf(mrun[m][r], mx);
        const float scl = exp2f((mrun[m][r] - mnew) * 1.442695041f);
        float ls = 0.f;
        #pragma unroll
        for (int n = 0; n < 4; ++n) {
          const float p = exp2f((sacc[m][n][r] - mnew) * 1.442695041f);
          sacc[m][n][r] = p;
          ls += p;
        }
        ls += __shfl_xor(ls, 1);
        ls += __shfl_xor(ls, 2);
        ls += __shfl_xor(ls, 4);
        ls += __shfl_xor(ls, 8);
        lrun[m][r] = lrun[m][r] * scl + ls;
        mrun[m][r] = mnew;
        #pragma unroll
        for (int nd = 0; nd < 4; ++nd) oacc[m][nd][r] *= scl;
      }

    // P -> LDS (acc layout) then re-read as A fragments
    #pragma unroll
    for (int m = 0; m < 2; ++m)
      #pragma unroll
      for (int n = 0; n < 4; ++n)
        #pragma unroll
        for (int r = 0; r < 4; ++r)
          sP[wv][m * 16 + g * 4 + r][n * 16 + fr] = (__bf16)sacc[m][n][r];

    #pragma unroll
    for (int ks = 0; ks < 2; ++ks) {
      bf16x8 pf[2];
      #pragma unroll
      for (int m = 0; m < 2; ++m)
        pf[m] = *(const bf16x8*)&sP[wv][m * 16 + fr][ks * 32 + g * 8];
      #pragma unroll
      for (int nd = 0; nd < 4; ++nd) {
        const int vrow = nd * 16 + fr;
        bf16x8 vf = *(const bf16x8*)&sV[vrow * 64 + ((ks * 32 + g * 8) ^ ((vrow & 7) * 8))];
        #pragma unroll
        for (int m = 0; m < 2; ++m)
          oacc[m][nd] = __builtin_amdgcn_mfma_f32_16x16x32_bf16(pf[m], vf, oacc[m][nd], 0, 0, 0);
      }
    }
    __syncthreads();
  }

  // normalize + write O in [b][s][h][d] (bf16) for the output projection
  #pragma unroll
  for (int m = 0; m < 2; ++m)
    #pragma unroll
    for (int r = 0; r < 4; ++r) {
      const float inv = 1.0f / lrun[m][r];
      const int q = qbase + m * 16 + g * 4 + r;
      #pragma unroll
      for (int nd = 0; nd < 4; ++nd)
        Ob[(size_t)(b * S_ + q) * D_ + h * HD_ + nd * 16 + fr] = (__bf16)(oacc[m][nd][r] * inv);
    }
}

// ---------------------------------------------------------------------------
extern "C" void kernel_launch(void* const* d_in, const int* in_sizes, int n_in,
                              void* d_out, int out_size, void* d_ws, size_t ws_size,
                              hipStream_t stream) {
  (void)in_sizes; (void)n_in; (void)out_size; (void)ws_size;
  const float* X  = (const float*)d_in[0];
  const unsigned char* pm = (const unsigned char*)d_in[1];
  const float* Wq = (const float*)d_in[2];
  const float* Wk = (const float*)d_in[3];
  const float* Wv = (const float*)d_in[4];
  const float* Wo = (const float*)d_in[5];
  const float* qs = (const float*)d_in[6];
  const float* ks = (const float*)d_in[7];
  const float* pd = (const float*)d_in[8];
  float* out = (float*)d_out;

  // workspace map (56 MB); Qr aliases Xb (dead after gemm1), Ob aliases QKV
  // (dead after rope/vtrans)
  char* ws = (char*)d_ws;
  int*    nm   = (int*)ws;                               // [0, 256)
  __bf16* Wqkv = (__bf16*)(ws + 256);                    // 3072x1024
  __bf16* Wob  = (__bf16*)(ws + 256 + 6291456);          // 1024x1024
  __bf16* Xb   = (__bf16*)(ws + 8388864);                // 4096x1024
  __bf16* QKV  = (__bf16*)(ws + 16777472);               // 4096x3072
  __bf16* Krb  = (__bf16*)(ws + 41943296);               // [b,h,s,d]
  __bf16* Vtb  = (__bf16*)(ws + 50331904);               // [b,h,d,s]
  __bf16* Qrb  = Xb;                                     // alias
  __bf16* Obuf = QKV;                                    // alias

  cvt_kernel<<<4096, 256, 0, stream>>>(X, Xb, 4194304);
  cvt_kernel<<<1024, 256, 0, stream>>>(Wq, Wqkv, 1048576);
  cvt_kernel<<<1024, 256, 0, stream>>>(Wk, Wqkv + 1048576, 1048576);
  cvt_kernel<<<1024, 256, 0, stream>>>(Wv, Wqkv + 2097152, 1048576);
  cvt_kernel<<<1024, 256, 0, stream>>>(Wo, Wob, 1048576);
  nm_kernel<<<4, 64, 0, stream>>>(pm, nm);

  // QKV = Xb @ Wqkv^T  (M=4096, N=3072, K=1024), bf16 out
  gemm_nt<true><<<dim3(24, 32), 256, 0, stream>>>(Xb, Wqkv, QKV, 3072, 1024);

  rope_rms<<<4096, 256, 0, stream>>>(QKV, Qrb, Krb, qs, ks, pd, nm);
  vtrans<<<dim3(16, H_, B_), 256, 0, stream>>>(QKV, Vtb);

  attn_fwd<<<dim3(8, H_, B_), 256, 0, stream>>>(Qrb, Krb, Vtb, Obuf, nm);

  // out = Obuf @ Wo^T  (M=4096, N=1024, K=1024), f32 out
  gemm_nt<false><<<dim3(8, 32), 256, 0, stream>>>(Obuf, Wob, out, 1024, 1024);
}

// Round 2
// 153.339 us; speedup vs baseline: 1.2405x; 1.2405x over previous
//
#include <hip/hip_runtime.h>
#include <hip/hip_bf16.h>
#include <stdint.h>

// Problem constants
#define B_  4
#define S_  1024
#define D_  1024
#define H_  16
#define HD_ 64

using f32x4  = __attribute__((ext_vector_type(4))) float;
using bf16x8 = __attribute__((ext_vector_type(8))) __bf16;
using bf16x4 = __attribute__((ext_vector_type(4))) __bf16;
using f32x4v = __attribute__((ext_vector_type(4))) float;

// ---------------------------------------------------------------------------
// global -> LDS direct load, 16B per lane. LDS dest must be wave-uniform base;
// HW writes lane i at base + i*16 (m104).
__device__ __forceinline__ void g2l16(const void* g, void* l) {
  using gp = const __attribute__((address_space(1))) unsigned int*;
  using lp = __attribute__((address_space(3))) unsigned int*;
  __builtin_amdgcn_global_load_lds((gp)(unsigned long long)g,
                                   (lp)(unsigned int)(unsigned long long)l,
                                   16, 0, 0);
}

// ---------------------------------------------------------------------------
// f32 -> bf16 conversion (vectorized, 4 elems/thread)
__global__ __launch_bounds__(256) void cvt_kernel(const float* __restrict__ in,
                                                  __bf16* __restrict__ out, int n) {
  int i = (blockIdx.x * 256 + threadIdx.x) * 4;
  if (i >= n) return;
  f32x4v v = *(const f32x4v*)(in + i);
  bf16x4 o;
  o[0] = (__bf16)v[0]; o[1] = (__bf16)v[1]; o[2] = (__bf16)v[2]; o[3] = (__bf16)v[3];
  *(bf16x4*)(out + i) = o;
}

// fused 4-weight cvt: blockIdx.y selects the weight (Wq,Wk,Wv -> Wqkv; Wo -> Wob)
__global__ __launch_bounds__(256)
void cvt4_kernel(const float* __restrict__ w0, const float* __restrict__ w1,
                 const float* __restrict__ w2, const float* __restrict__ w3,
                 __bf16* __restrict__ Wqkv, __bf16* __restrict__ Wob) {
  const int y = blockIdx.y;
  const float* src = (y == 0) ? w0 : (y == 1) ? w1 : (y == 2) ? w2 : w3;
  __bf16* dst = (y < 3) ? (Wqkv + (size_t)y * 1048576) : Wob;
  int i = (blockIdx.x * 256 + threadIdx.x) * 4;
  f32x4v v = *(const f32x4v*)(src + i);
  bf16x4 o;
  o[0] = (__bf16)v[0]; o[1] = (__bf16)v[1]; o[2] = (__bf16)v[2]; o[3] = (__bf16)v[3];
  *(bf16x4*)(dst + i) = o;
}

// num_masked per batch
__global__ __launch_bounds__(64) void nm_kernel(const unsigned char* __restrict__ m,
                                                int* __restrict__ nm) {
  int b = blockIdx.x, t = threadIdx.x;
  int s = 0;
  for (int i = t; i < S_; i += 64) s += (m[b * S_ + i] != 0) ? 1 : 0;
  #pragma unroll
  for (int k = 1; k < 64; k <<= 1) s += __shfl_xor(s, k);
  if (t == 0) nm[b] = s;
}

// ---------------------------------------------------------------------------
// NT GEMM: C[M,N] = A[M,K] * B[N,K]^T, bf16 in, f32 acc. m97 structure.
template <bool OUT_BF16>
__global__ __launch_bounds__(256)
void gemm_nt(const __bf16* __restrict__ A, const __bf16* __restrict__ Bm,
             void* __restrict__ Cv, int N, int K) {
  __shared__ __bf16 sA[128 * 32];
  __shared__ __bf16 sB[128 * 32];
  const int tid = threadIdx.x;
  const int wv = tid >> 6, lane = tid & 63;
  const int row0 = blockIdx.y * 128, col0 = blockIdx.x * 128;
  const int wm = wv >> 1, wn = wv & 1;
  const int c0 = wv * 2, c1 = c0 + 1;
  const int srow = lane >> 2;
  const int scol = (lane & 3) * 8;
  const __bf16* Ab = A + (size_t)(row0 + srow) * K + scol;
  const __bf16* Bb = Bm + (size_t)(col0 + srow) * K + scol;
  const int fr = lane & 15, fk = (lane >> 4) * 8;

  f32x4 acc[4][4] = {};

  for (int k0 = 0; k0 < K; k0 += 32) {
    g2l16(Ab + (size_t)(c0 * 16) * K + k0, &sA[c0 * 512]);
    g2l16(Ab + (size_t)(c1 * 16) * K + k0, &sA[c1 * 512]);
    g2l16(Bb + (size_t)(c0 * 16) * K + k0, &sB[c0 * 512]);
    g2l16(Bb + (size_t)(c1 * 16) * K + k0, &sB[c1 * 512]);
    __syncthreads();

    bf16x8 af[4], bfr[4];
    #pragma unroll
    for (int m = 0; m < 4; ++m)
      af[m] = *(const bf16x8*)&sA[(wm * 64 + m * 16 + fr) * 32 + fk];
    #pragma unroll
    for (int n = 0; n < 4; ++n)
      bfr[n] = *(const bf16x8*)&sB[(wn * 64 + n * 16 + fr) * 32 + fk];

    #pragma unroll
    for (int m = 0; m < 4; ++m)
      #pragma unroll
      for (int n = 0; n < 4; ++n)
        acc[m][n] = __builtin_amdgcn_mfma_f32_16x16x32_bf16(af[m], bfr[n], acc[m][n], 0, 0, 0);

    __syncthreads();
  }

  const int g4 = (lane >> 4) * 4;
  if (OUT_BF16) {
    __bf16* C = (__bf16*)Cv;
    #pragma unroll
    for (int m = 0; m < 4; ++m)
      #pragma unroll
      for (int n = 0; n < 4; ++n)
        #pragma unroll
        for (int r = 0; r < 4; ++r)
          C[(size_t)(row0 + wm * 64 + m * 16 + g4 + r) * N + col0 + wn * 64 + n * 16 + fr] =
              (__bf16)acc[m][n][r];
  } else {
    float* C = (float*)Cv;
    #pragma unroll
    for (int m = 0; m < 4; ++m)
      #pragma unroll
      for (int n = 0; n < 4; ++n)
        #pragma unroll
        for (int r = 0; r < 4; ++r)
          C[(size_t)(row0 + wm * 64 + m * 16 + g4 + r) * N + col0 + wn * 64 + n * 16 + fr] =
              acc[m][n][r];
  }
}

// ---------------------------------------------------------------------------
// RoPE + RMSNorm + q per-dim scale. Block = one (b,s).
// NOTE: q is pre-scaled by LOG2E^2/8 * softplus (extra LOG2E so attention's
// softmax can use exp2 directly on raw scores).
__global__ __launch_bounds__(256)
void rope_rms(const __bf16* __restrict__ QKV, __bf16* __restrict__ Qr,
              __bf16* __restrict__ Kr, const float* __restrict__ qsc,
              const float* __restrict__ ksc, const float* __restrict__ pds,
              const int* __restrict__ nm) {
  const int bs = blockIdx.x;
  const int b = bs >> 10, s = bs & 1023;
  const int t = threadIdx.x;
  const bool isK = t >= 128;
  const int t2 = t & 127;
  const int h = t2 >> 3, j = t2 & 7;

  const __bf16* src = QKV + (size_t)bs * 3072 + (isK ? 1024 : 0) + h * 64 + j * 8;
  bf16x8 xv = *(const bf16x8*)src;
  float f[8], of[8];
  #pragma unroll
  for (int i = 0; i < 8; ++i) f[i] = (float)xv[i];

  const float pos = (float)s - (float)nm[b];
  #pragma unroll
  for (int i = 0; i < 8; ++i) {
    const float other = __shfl_xor(f[i], 4);
    const float frc = (float)((j & 3) * 8 + i) * (1.0f / 32.0f);
    const float ang = pos * exp2f(frc * -13.287712379549449f); // 1/10000^frc
    float sn, cs;
    sincosf(ang, &sn, &cs);
    of[i] = (j & 4) ? (f[i] * cs + other * sn)
                    : (f[i] * cs - other * sn);
  }

  float ss = 0.f;
  #pragma unroll
  for (int i = 0; i < 8; ++i) ss += of[i] * of[i];
  ss += __shfl_xor(ss, 1);
  ss += __shfl_xor(ss, 2);
  ss += __shfl_xor(ss, 4);
  const float rn = rsqrtf(ss * (1.0f / 64.0f) + 1e-6f);

  const float* sc = isK ? ksc : qsc;
  bf16x8 ov;
  #pragma unroll
  for (int i = 0; i < 8; ++i) {
    const int d = j * 8 + i;
    float v = of[i] * rn * sc[d];
    // LOG2E^2 / 8 * softplus(pds): scores land directly in log2 domain
    if (!isK) v *= 0.26017112262570096f * log1pf(expf(pds[d]));
    ov[i] = (__bf16)v;
  }
  __bf16* dst = (isK ? Kr : Qr) + ((size_t)(b * H_ + h) * S_ + s) * HD_ + j * 8;
  *(bf16x8*)dst = ov;
}

// ---------------------------------------------------------------------------
// V transpose: QKV[:, 2048 + h*64 + d] -> Vt[b][h][d][s]
__global__ __launch_bounds__(256)
void vtrans(const __bf16* __restrict__ QKV, __bf16* __restrict__ Vt) {
  const int st = blockIdx.x, h = blockIdx.y, b = blockIdx.z;
  __shared__ __bf16 tile[64][72];
  const int t = threadIdx.x;
  const int r = t >> 2, q = t & 3;

  const __bf16* src = QKV + (size_t)(b * S_ + st * 64 + r) * 3072 + 2048 + h * 64 + q * 16;
  bf16x8 v0 = *(const bf16x8*)src;
  bf16x8 v1 = *(const bf16x8*)(src + 8);
  *(bf16x8*)&tile[r][q * 16] = v0;
  *(bf16x8*)&tile[r][q * 16 + 8] = v1;
  __syncthreads();

  __bf16 outv[16];
  #pragma unroll
  for (int i = 0; i < 16; ++i) outv[i] = tile[q * 16 + i][r];
  __bf16* dst = Vt + ((size_t)(b * H_ + h) * HD_ + r) * S_ + st * 64 + q * 16;
  *(bf16x8*)dst = *(bf16x8*)&outv[0];
  *(bf16x8*)(dst + 8) = *(bf16x8*)&outv[8];
}

// ---------------------------------------------------------------------------
// Flash attention v2: block = 64 q rows (4 waves x 16 rows), grid = 1024
// 1D blocks (16 q-blocks x 64 bh), ALL co-resident (~25.6KB LDS, low VGPR)
// -> 16 waves/CU. q-blocks dispatched longest-first (causal).
__global__ __launch_bounds__(256)
void attn_fwd(const __bf16* __restrict__ Qr, const __bf16* __restrict__ Kr,
              const __bf16* __restrict__ Vt, __bf16* __restrict__ Ob,
              const int* __restrict__ nm) {
  const int bid = blockIdx.x;
  const int qblk = 15 - (bid >> 6);      // longest blocks dispatch first
  const int bh = bid & 63;
  const int b = bh >> 4, h = bh & 15;
  const int q0 = qblk * 64;
  const int tid = threadIdx.x, wv = tid >> 6, lane = tid & 63;

  __shared__ __bf16 sK[64 * 64];
  __shared__ __bf16 sV[64 * 64];
  __shared__ __bf16 sP[4][16][72];

  const size_t bhs = (size_t)(b * H_ + h);
  const __bf16* Qh = Qr + bhs * (S_ * HD_);
  const __bf16* Kh = Kr + bhs * (S_ * HD_);
  const __bf16* Vh = Vt + bhs * (HD_ * S_);

  const int fr = lane & 15, g = lane >> 4;
  const int qbase = q0 + wv * 16;

  bf16x8 qf[2];
  #pragma unroll
  for (int ks = 0; ks < 2; ++ks)
    qf[ks] = *(const bf16x8*)&Qh[(size_t)(qbase + fr) * HD_ + ks * 32 + g * 8];

  f32x4 oacc[4] = {};
  float mrun[4], lrun[4];
  #pragma unroll
  for (int r = 0; r < 4; ++r) { mrun[r] = -3e38f; lrun[r] = 0.f; }

  const int nmb = nm[b];
  const int srow = lane >> 3;
  const int ssw = ((lane & 7) ^ srow) * 8;   // inverse-swizzled source col
  const int c0 = wv * 2, c1 = c0 + 1;

  for (int kv0 = 0; kv0 < q0 + 64; kv0 += 64) {
    g2l16(&Kh[(size_t)(kv0 + c0 * 8 + srow) * HD_ + ssw], &sK[c0 * 512]);
    g2l16(&Kh[(size_t)(kv0 + c1 * 8 + srow) * HD_ + ssw], &sK[c1 * 512]);
    g2l16(&Vh[(size_t)(c0 * 8 + srow) * S_ + kv0 + ssw], &sV[c0 * 512]);
    g2l16(&Vh[(size_t)(c1 * 8 + srow) * S_ + kv0 + ssw], &sV[c1 * 512]);
    __syncthreads();

    // S = Q K^T
    f32x4 sacc[4] = {};
    #pragma unroll
    for (int n = 0; n < 4; ++n) {
      const int krow = n * 16 + fr;
      #pragma unroll
      for (int ks = 0; ks < 2; ++ks) {
        bf16x8 kf = *(const bf16x8*)&sK[krow * 64 + ((ks * 32 + g * 8) ^ ((krow & 7) * 8))];
        sacc[n] = __builtin_amdgcn_mfma_f32_16x16x32_bf16(qf[ks], kf, sacc[n], 0, 0, 0);
      }
    }

    // mask
    const bool fullv = (qbase >= kv0 + 63) && (kv0 >= nmb);
    if (!fullv) {
      #pragma unroll
      for (int n = 0; n < 4; ++n) {
        const int kv = kv0 + n * 16 + fr;
        #pragma unroll
        for (int r = 0; r < 4; ++r) {
          const int q = qbase + g * 4 + r;
          if (q < kv || kv < nmb) sacc[n][r] = -1e30f;
        }
      }
    }

    // online softmax (scores already in log2 domain)
    #pragma unroll
    for (int r = 0; r < 4; ++r) {
      float mx = fmaxf(fmaxf(sacc[0][r], sacc[1][r]), fmaxf(sacc[2][r], sacc[3][r]));
      mx = fmaxf(mx, __shfl_xor(mx, 1));
      mx = fmaxf(mx, __shfl_xor(mx, 2));
      mx = fmaxf(mx, __shfl_xor(mx, 4));
      mx = fmaxf(mx, __shfl_xor(mx, 8));
      const float mnew = fmaxf(mrun[r], mx);
      const float scl = exp2f(mrun[r] - mnew);
      float ls = 0.f;
      #pragma unroll
      for (int n = 0; n < 4; ++n) {
        const float p = exp2f(sacc[n][r] - mnew);
        sacc[n][r] = p;
        ls += p;
      }
      ls += __shfl_xor(ls, 1);
      ls += __shfl_xor(ls, 2);
      ls += __shfl_xor(ls, 4);
      ls += __shfl_xor(ls, 8);
      lrun[r] = lrun[r] * scl + ls;
      mrun[r] = mnew;
      #pragma unroll
      for (int nd = 0; nd < 4; ++nd) oacc[nd][r] *= scl;
    }

    // P -> wave-private LDS, re-read as A fragments
    #pragma unroll
    for (int n = 0; n < 4; ++n)
      #pragma unroll
      for (int r = 0; r < 4; ++r)
        sP[wv][g * 4 + r][n * 16 + fr] = (__bf16)sacc[n][r];

    #pragma unroll
    for (int ks = 0; ks < 2; ++ks) {
      bf16x8 pf = *(const bf16x8*)&sP[wv][fr][ks * 32 + g * 8];
      #pragma unroll
      for (int nd = 0; nd < 4; ++nd) {
        const int vrow = nd * 16 + fr;
        bf16x8 vf = *(const bf16x8*)&sV[vrow * 64 + ((ks * 32 + g * 8) ^ ((vrow & 7) * 8))];
        oacc[nd] = __builtin_amdgcn_mfma_f32_16x16x32_bf16(pf, vf, oacc[nd], 0, 0, 0);
      }
    }
    __syncthreads();
  }

  #pragma unroll
  for (int r = 0; r < 4; ++r) {
    const float inv = 1.0f / lrun[r];
    const int q = qbase + g * 4 + r;
    #pragma unroll
    for (int nd = 0; nd < 4; ++nd)
      Ob[(size_t)(b * S_ + q) * D_ + h * HD_ + nd * 16 + fr] = (__bf16)(oacc[nd][r] * inv);
  }
}

// ---------------------------------------------------------------------------
extern "C" void kernel_launch(void* const* d_in, const int* in_sizes, int n_in,
                              void* d_out, int out_size, void* d_ws, size_t ws_size,
                              hipStream_t stream) {
  (void)in_sizes; (void)n_in; (void)out_size; (void)ws_size;
  const float* X  = (const float*)d_in[0];
  const unsigned char* pm = (const unsigned char*)d_in[1];
  const float* Wq = (const float*)d_in[2];
  const float* Wk = (const float*)d_in[3];
  const float* Wv = (const float*)d_in[4];
  const float* Wo = (const float*)d_in[5];
  const float* qs = (const float*)d_in[6];
  const float* ks = (const float*)d_in[7];
  const float* pd = (const float*)d_in[8];
  float* out = (float*)d_out;

  char* ws = (char*)d_ws;
  int*    nm   = (int*)ws;                               // [0, 256)
  __bf16* Wqkv = (__bf16*)(ws + 256);                    // 3072x1024
  __bf16* Wob  = (__bf16*)(ws + 256 + 6291456);          // 1024x1024
  __bf16* Xb   = (__bf16*)(ws + 8388864);                // 4096x1024
  __bf16* QKV  = (__bf16*)(ws + 16777472);               // 4096x3072
  __bf16* Krb  = (__bf16*)(ws + 41943296);               // [b,h,s,d]
  __bf16* Vtb  = (__bf16*)(ws + 50331904);               // [b,h,d,s]
  __bf16* Qrb  = Xb;                                     // alias
  __bf16* Obuf = QKV;                                    // alias

  cvt_kernel<<<4096, 256, 0, stream>>>(X, Xb, 4194304);
  cvt4_kernel<<<dim3(1024, 4), 256, 0, stream>>>(Wq, Wk, Wv, Wo, Wqkv, Wob);
  nm_kernel<<<4, 64, 0, stream>>>(pm, nm);

  // QKV = Xb @ Wqkv^T  (M=4096, N=3072, K=1024)
  gemm_nt<true><<<dim3(24, 32), 256, 0, stream>>>(Xb, Wqkv, QKV, 3072, 1024);

  rope_rms<<<4096, 256, 0, stream>>>(QKV, Qrb, Krb, qs, ks, pd, nm);
  vtrans<<<dim3(16, H_, B_), 256, 0, stream>>>(QKV, Vtb);

  attn_fwd<<<1024, 256, 0, stream>>>(Qrb, Krb, Vtb, Obuf, nm);

  // out = Obuf @ Wo^T  (M=4096, N=1024, K=1024)
  gemm_nt<false><<<dim3(8, 32), 256, 0, stream>>>(Obuf, Wob, out, 1024, 1024);
}

// Round 3
// 139.083 us; speedup vs baseline: 1.3677x; 1.1025x over previous
//
#include <hip/hip_runtime.h>
#include <hip/hip_bf16.h>
#include <stdint.h>

// Problem constants
#define B_  4
#define S_  1024
#define D_  1024
#define H_  16
#define HD_ 64

using f32x4  = __attribute__((ext_vector_type(4))) float;
using bf16x8 = __attribute__((ext_vector_type(8))) __bf16;
using bf16x4 = __attribute__((ext_vector_type(4))) __bf16;
using f32x4v = __attribute__((ext_vector_type(4))) float;

// ---------------------------------------------------------------------------
// global -> LDS direct load, 16B per lane. LDS dest must be wave-uniform base;
// HW writes lane i at base + i*16 (m104).
__device__ __forceinline__ void g2l16(const void* g, void* l) {
  using gp = const __attribute__((address_space(1))) unsigned int*;
  using lp = __attribute__((address_space(3))) unsigned int*;
  __builtin_amdgcn_global_load_lds((gp)(unsigned long long)g,
                                   (lp)(unsigned int)(unsigned long long)l,
                                   16, 0, 0);
}

// ---------------------------------------------------------------------------
// f32 -> bf16 conversion (vectorized, 4 elems/thread)
__global__ __launch_bounds__(256) void cvt_kernel(const float* __restrict__ in,
                                                  __bf16* __restrict__ out, int n) {
  int i = (blockIdx.x * 256 + threadIdx.x) * 4;
  if (i >= n) return;
  f32x4v v = *(const f32x4v*)(in + i);
  bf16x4 o;
  o[0] = (__bf16)v[0]; o[1] = (__bf16)v[1]; o[2] = (__bf16)v[2]; o[3] = (__bf16)v[3];
  *(bf16x4*)(out + i) = o;
}

// fused 4-weight cvt: blockIdx.y selects the weight (Wq,Wk,Wv -> Wqkv; Wo -> Wob)
__global__ __launch_bounds__(256)
void cvt4_kernel(const float* __restrict__ w0, const float* __restrict__ w1,
                 const float* __restrict__ w2, const float* __restrict__ w3,
                 __bf16* __restrict__ Wqkv, __bf16* __restrict__ Wob) {
  const int y = blockIdx.y;
  const float* src = (y == 0) ? w0 : (y == 1) ? w1 : (y == 2) ? w2 : w3;
  __bf16* dst = (y < 3) ? (Wqkv + (size_t)y * 1048576) : Wob;
  int i = (blockIdx.x * 256 + threadIdx.x) * 4;
  f32x4v v = *(const f32x4v*)(src + i);
  bf16x4 o;
  o[0] = (__bf16)v[0]; o[1] = (__bf16)v[1]; o[2] = (__bf16)v[2]; o[3] = (__bf16)v[3];
  *(bf16x4*)(dst + i) = o;
}

// num_masked per batch
__global__ __launch_bounds__(64) void nm_kernel(const unsigned char* __restrict__ m,
                                                int* __restrict__ nm) {
  int b = blockIdx.x, t = threadIdx.x;
  int s = 0;
  for (int i = t; i < S_; i += 64) s += (m[b * S_ + i] != 0) ? 1 : 0;
  #pragma unroll
  for (int k = 1; k < 64; k <<= 1) s += __shfl_xor(s, k);
  if (t == 0) nm[b] = s;
}

// ---------------------------------------------------------------------------
// NT GEMM: C[M,N] = A[M,K] * B[N,K]^T, bf16 in, f32 acc.
// 128x128 tile, BK=32, prefetch double-buffered LDS (one barrier per K-step),
// bank-conflict XOR swizzle (slot ^= (row>>1)&3) applied source-side + read-side.
template <bool OUT_BF16>
__global__ __launch_bounds__(256)
void gemm_nt(const __bf16* __restrict__ A, const __bf16* __restrict__ Bm,
             void* __restrict__ Cv, int N, int K) {
  __shared__ __bf16 sA[2][128 * 32];
  __shared__ __bf16 sB[2][128 * 32];
  const int tid = threadIdx.x;
  const int wv = tid >> 6, lane = tid & 63;
  const int row0 = blockIdx.y * 128, col0 = blockIdx.x * 128;
  const int wm = wv >> 1, wn = wv & 1;
  const int c0 = wv * 2, c1 = c0 + 1;
  const int srow = lane >> 2;                               // row within 16-row chunk
  const int scol = (((lane & 3) ^ ((lane >> 3) & 3))) * 8;  // swizzled source slot
  const __bf16* Ab = A + (size_t)(row0 + srow) * K + scol;
  const __bf16* Bb = Bm + (size_t)(col0 + srow) * K + scol;
  const int fr = lane & 15;
  const int fk = ((lane >> 4) ^ ((fr >> 1) & 3)) * 8;       // swizzled read col

  f32x4 acc[4][4] = {};

#define GSTAGE(buf, k0) do {                                              \
    g2l16(Ab + (size_t)(c0 * 16) * K + (k0), &sA[buf][c0 * 512]);         \
    g2l16(Ab + (size_t)(c1 * 16) * K + (k0), &sA[buf][c1 * 512]);         \
    g2l16(Bb + (size_t)(c0 * 16) * K + (k0), &sB[buf][c0 * 512]);         \
    g2l16(Bb + (size_t)(c1 * 16) * K + (k0), &sB[buf][c1 * 512]);         \
  } while (0)

  GSTAGE(0, 0);
  __syncthreads();
  int cur = 0;
  for (int k0 = 0; k0 < K; k0 += 32) {
    if (k0 + 32 < K) GSTAGE(cur ^ 1, k0 + 32);   // prefetch next tile

    bf16x8 af[4], bfr[4];
    #pragma unroll
    for (int m = 0; m < 4; ++m)
      af[m] = *(const bf16x8*)&sA[cur][(wm * 64 + m * 16 + fr) * 32 + fk];
    #pragma unroll
    for (int n = 0; n < 4; ++n)
      bfr[n] = *(const bf16x8*)&sB[cur][(wn * 64 + n * 16 + fr) * 32 + fk];

    #pragma unroll
    for (int m = 0; m < 4; ++m)
      #pragma unroll
      for (int n = 0; n < 4; ++n)
        acc[m][n] = __builtin_amdgcn_mfma_f32_16x16x32_bf16(af[m], bfr[n], acc[m][n], 0, 0, 0);

    __syncthreads();   // single barrier: drains prefetch vmcnt + protects buffers
    cur ^= 1;
  }
#undef GSTAGE

  const int g4 = (lane >> 4) * 4;
  if (OUT_BF16) {
    __bf16* C = (__bf16*)Cv;
    #pragma unroll
    for (int m = 0; m < 4; ++m)
      #pragma unroll
      for (int n = 0; n < 4; ++n)
        #pragma unroll
        for (int r = 0; r < 4; ++r)
          C[(size_t)(row0 + wm * 64 + m * 16 + g4 + r) * N + col0 + wn * 64 + n * 16 + fr] =
              (__bf16)acc[m][n][r];
  } else {
    float* C = (float*)Cv;
    #pragma unroll
    for (int m = 0; m < 4; ++m)
      #pragma unroll
      for (int n = 0; n < 4; ++n)
        #pragma unroll
        for (int r = 0; r < 4; ++r)
          C[(size_t)(row0 + wm * 64 + m * 16 + g4 + r) * N + col0 + wn * 64 + n * 16 + fr] =
              acc[m][n][r];
  }
}

// ---------------------------------------------------------------------------
// RoPE + RMSNorm + q per-dim scale. Block = one (b,s).
// q is pre-scaled by LOG2E^2/8 * softplus so attention scores are log2-domain.
__global__ __launch_bounds__(256)
void rope_rms(const __bf16* __restrict__ QKV, __bf16* __restrict__ Qr,
              __bf16* __restrict__ Kr, const float* __restrict__ qsc,
              const float* __restrict__ ksc, const float* __restrict__ pds,
              const int* __restrict__ nm) {
  const int bs = blockIdx.x;
  const int b = bs >> 10, s = bs & 1023;
  const int t = threadIdx.x;
  const bool isK = t >= 128;
  const int t2 = t & 127;
  const int h = t2 >> 3, j = t2 & 7;

  const __bf16* src = QKV + (size_t)bs * 3072 + (isK ? 1024 : 0) + h * 64 + j * 8;
  bf16x8 xv = *(const bf16x8*)src;
  float f[8], of[8];
  #pragma unroll
  for (int i = 0; i < 8; ++i) f[i] = (float)xv[i];

  const float pos = (float)s - (float)nm[b];
  #pragma unroll
  for (int i = 0; i < 8; ++i) {
    const float other = __shfl_xor(f[i], 4);
    const float frc = (float)((j & 3) * 8 + i) * (1.0f / 32.0f);
    const float ang = pos * exp2f(frc * -13.287712379549449f); // 1/10000^frc
    float sn, cs;
    sincosf(ang, &sn, &cs);
    of[i] = (j & 4) ? (f[i] * cs + other * sn)
                    : (f[i] * cs - other * sn);
  }

  float ss = 0.f;
  #pragma unroll
  for (int i = 0; i < 8; ++i) ss += of[i] * of[i];
  ss += __shfl_xor(ss, 1);
  ss += __shfl_xor(ss, 2);
  ss += __shfl_xor(ss, 4);
  const float rn = rsqrtf(ss * (1.0f / 64.0f) + 1e-6f);

  const float* sc = isK ? ksc : qsc;
  bf16x8 ov;
  #pragma unroll
  for (int i = 0; i < 8; ++i) {
    const int d = j * 8 + i;
    float v = of[i] * rn * sc[d];
    if (!isK) v *= 0.26017112262570096f * log1pf(expf(pds[d])); // LOG2E^2/8 * softplus
    ov[i] = (__bf16)v;
  }
  __bf16* dst = (isK ? Kr : Qr) + ((size_t)(b * H_ + h) * S_ + s) * HD_ + j * 8;
  *(bf16x8*)dst = ov;
}

// ---------------------------------------------------------------------------
// V transpose: QKV[:, 2048 + h*64 + d] -> Vt[b][h][d][s]
__global__ __launch_bounds__(256)
void vtrans(const __bf16* __restrict__ QKV, __bf16* __restrict__ Vt) {
  const int st = blockIdx.x, h = blockIdx.y, b = blockIdx.z;
  __shared__ __bf16 tile[64][72];
  const int t = threadIdx.x;
  const int r = t >> 2, q = t & 3;

  const __bf16* src = QKV + (size_t)(b * S_ + st * 64 + r) * 3072 + 2048 + h * 64 + q * 16;
  bf16x8 v0 = *(const bf16x8*)src;
  bf16x8 v1 = *(const bf16x8*)(src + 8);
  *(bf16x8*)&tile[r][q * 16] = v0;
  *(bf16x8*)&tile[r][q * 16 + 8] = v1;
  __syncthreads();

  __bf16 outv[16];
  #pragma unroll
  for (int i = 0; i < 16; ++i) outv[i] = tile[q * 16 + i][r];
  __bf16* dst = Vt + ((size_t)(b * H_ + h) * HD_ + r) * S_ + st * 64 + q * 16;
  *(bf16x8*)dst = *(bf16x8*)&outv[0];
  *(bf16x8*)(dst + 8) = *(bf16x8*)&outv[8];
}

// ---------------------------------------------------------------------------
// Flash attention v3: block = 64 q rows (4 waves x 16 rows), grid = 1024
// blocks (16 q-blocks x 64 bh), q-blocks longest-first. Prefetch
// double-buffered K/V staging: one vmcnt(0)+barrier per KV tile (T3-min).
__global__ __launch_bounds__(256)
void attn_fwd(const __bf16* __restrict__ Qr, const __bf16* __restrict__ Kr,
              const __bf16* __restrict__ Vt, __bf16* __restrict__ Ob,
              const int* __restrict__ nm) {
  const int bid = blockIdx.x;
  const int qblk = 15 - (bid >> 6);      // longest blocks dispatch first
  const int bh = bid & 63;
  const int b = bh >> 4, h = bh & 15;
  const int q0 = qblk * 64;
  const int tid = threadIdx.x, wv = tid >> 6, lane = tid & 63;

  __shared__ __bf16 sK[2][64 * 64];
  __shared__ __bf16 sV[2][64 * 64];
  __shared__ __bf16 sP[4][16][72];

  const size_t bhs = (size_t)(b * H_ + h);
  const __bf16* Qh = Qr + bhs * (S_ * HD_);
  const __bf16* Kh = Kr + bhs * (S_ * HD_);
  const __bf16* Vh = Vt + bhs * (HD_ * S_);

  const int fr = lane & 15, g = lane >> 4;
  const int qbase = q0 + wv * 16;

  bf16x8 qf[2];
  #pragma unroll
  for (int ks = 0; ks < 2; ++ks)
    qf[ks] = *(const bf16x8*)&Qh[(size_t)(qbase + fr) * HD_ + ks * 32 + g * 8];

  f32x4 oacc[4] = {};
  float mrun[4], lrun[4];
  #pragma unroll
  for (int r = 0; r < 4; ++r) { mrun[r] = -3e38f; lrun[r] = 0.f; }

  const int nmb = nm[b];
  const int srow = lane >> 3;
  const int ssw = ((lane & 7) ^ srow) * 8;   // inverse-swizzled source col
  const int c0 = wv * 2, c1 = c0 + 1;

#define ASTAGE(buf, kv) do {                                                    \
    g2l16(&Kh[(size_t)((kv) + c0 * 8 + srow) * HD_ + ssw], &sK[buf][c0 * 512]); \
    g2l16(&Kh[(size_t)((kv) + c1 * 8 + srow) * HD_ + ssw], &sK[buf][c1 * 512]); \
    g2l16(&Vh[(size_t)(c0 * 8 + srow) * S_ + (kv) + ssw], &sV[buf][c0 * 512]);  \
    g2l16(&Vh[(size_t)(c1 * 8 + srow) * S_ + (kv) + ssw], &sV[buf][c1 * 512]);  \
  } while (0)

  ASTAGE(0, 0);
  __syncthreads();
  int cur = 0;
  const int kvend = q0 + 64;

  for (int kv0 = 0; kv0 < kvend; kv0 += 64) {
    if (kv0 + 64 < kvend) ASTAGE(cur ^ 1, kv0 + 64);   // prefetch next tile

    // S = Q K^T
    f32x4 sacc[4] = {};
    #pragma unroll
    for (int n = 0; n < 4; ++n) {
      const int krow = n * 16 + fr;
      #pragma unroll
      for (int ks = 0; ks < 2; ++ks) {
        bf16x8 kf = *(const bf16x8*)&sK[cur][krow * 64 + ((ks * 32 + g * 8) ^ ((krow & 7) * 8))];
        sacc[n] = __builtin_amdgcn_mfma_f32_16x16x32_bf16(qf[ks], kf, sacc[n], 0, 0, 0);
      }
    }

    // mask
    const bool fullv = (qbase >= kv0 + 63) && (kv0 >= nmb);
    if (!fullv) {
      #pragma unroll
      for (int n = 0; n < 4; ++n) {
        const int kv = kv0 + n * 16 + fr;
        #pragma unroll
        for (int r = 0; r < 4; ++r) {
          const int q = qbase + g * 4 + r;
          if (q < kv || kv < nmb) sacc[n][r] = -1e30f;
        }
      }
    }

    // online softmax (scores already in log2 domain)
    #pragma unroll
    for (int r = 0; r < 4; ++r) {
      float mx = fmaxf(fmaxf(sacc[0][r], sacc[1][r]), fmaxf(sacc[2][r], sacc[3][r]));
      mx = fmaxf(mx, __shfl_xor(mx, 1));
      mx = fmaxf(mx, __shfl_xor(mx, 2));
      mx = fmaxf(mx, __shfl_xor(mx, 4));
      mx = fmaxf(mx, __shfl_xor(mx, 8));
      const float mnew = fmaxf(mrun[r], mx);
      const float scl = exp2f(mrun[r] - mnew);
      float ls = 0.f;
      #pragma unroll
      for (int n = 0; n < 4; ++n) {
        const float p = exp2f(sacc[n][r] - mnew);
        sacc[n][r] = p;
        ls += p;
      }
      ls += __shfl_xor(ls, 1);
      ls += __shfl_xor(ls, 2);
      ls += __shfl_xor(ls, 4);
      ls += __shfl_xor(ls, 8);
      lrun[r] = lrun[r] * scl + ls;
      mrun[r] = mnew;
      #pragma unroll
      for (int nd = 0; nd < 4; ++nd) oacc[nd][r] *= scl;
    }

    // P -> wave-private LDS, re-read as A fragments
    #pragma unroll
    for (int n = 0; n < 4; ++n)
      #pragma unroll
      for (int r = 0; r < 4; ++r)
        sP[wv][g * 4 + r][n * 16 + fr] = (__bf16)sacc[n][r];

    #pragma unroll
    for (int ks = 0; ks < 2; ++ks) {
      bf16x8 pf = *(const bf16x8*)&sP[wv][fr][ks * 32 + g * 8];
      #pragma unroll
      for (int nd = 0; nd < 4; ++nd) {
        const int vrow = nd * 16 + fr;
        bf16x8 vf = *(const bf16x8*)&sV[cur][vrow * 64 + ((ks * 32 + g * 8) ^ ((vrow & 7) * 8))];
        oacc[nd] = __builtin_amdgcn_mfma_f32_16x16x32_bf16(pf, vf, oacc[nd], 0, 0, 0);
      }
    }
    __syncthreads();   // single barrier: drains prefetch + protects buffers
    cur ^= 1;
  }
#undef ASTAGE

  #pragma unroll
  for (int r = 0; r < 4; ++r) {
    const float inv = 1.0f / lrun[r];
    const int q = qbase + g * 4 + r;
    #pragma unroll
    for (int nd = 0; nd < 4; ++nd)
      Ob[(size_t)(b * S_ + q) * D_ + h * HD_ + nd * 16 + fr] = (__bf16)(oacc[nd][r] * inv);
  }
}

// ---------------------------------------------------------------------------
extern "C" void kernel_launch(void* const* d_in, const int* in_sizes, int n_in,
                              void* d_out, int out_size, void* d_ws, size_t ws_size,
                              hipStream_t stream) {
  (void)in_sizes; (void)n_in; (void)out_size; (void)ws_size;
  const float* X  = (const float*)d_in[0];
  const unsigned char* pm = (const unsigned char*)d_in[1];
  const float* Wq = (const float*)d_in[2];
  const float* Wk = (const float*)d_in[3];
  const float* Wv = (const float*)d_in[4];
  const float* Wo = (const float*)d_in[5];
  const float* qs = (const float*)d_in[6];
  const float* ks = (const float*)d_in[7];
  const float* pd = (const float*)d_in[8];
  float* out = (float*)d_out;

  char* ws = (char*)d_ws;
  int*    nm   = (int*)ws;                               // [0, 256)
  __bf16* Wqkv = (__bf16*)(ws + 256);                    // 3072x1024
  __bf16* Wob  = (__bf16*)(ws + 256 + 6291456);          // 1024x1024
  __bf16* Xb   = (__bf16*)(ws + 8388864);                // 4096x1024
  __bf16* QKV  = (__bf16*)(ws + 16777472);               // 4096x3072
  __bf16* Krb  = (__bf16*)(ws + 41943296);               // [b,h,s,d]
  __bf16* Vtb  = (__bf16*)(ws + 50331904);               // [b,h,d,s]
  __bf16* Qrb  = Xb;                                     // alias
  __bf16* Obuf = QKV;                                    // alias

  cvt_kernel<<<4096, 256, 0, stream>>>(X, Xb, 4194304);
  cvt4_kernel<<<dim3(1024, 4), 256, 0, stream>>>(Wq, Wk, Wv, Wo, Wqkv, Wob);
  nm_kernel<<<4, 64, 0, stream>>>(pm, nm);

  // QKV = Xb @ Wqkv^T  (M=4096, N=3072, K=1024)
  gemm_nt<true><<<dim3(24, 32), 256, 0, stream>>>(Xb, Wqkv, QKV, 3072, 1024);

  rope_rms<<<4096, 256, 0, stream>>>(QKV, Qrb, Krb, qs, ks, pd, nm);
  vtrans<<<dim3(16, H_, B_), 256, 0, stream>>>(QKV, Vtb);

  attn_fwd<<<1024, 256, 0, stream>>>(Qrb, Krb, Vtb, Obuf, nm);

  // out = Obuf @ Wo^T  (M=4096, N=1024, K=1024)
  gemm_nt<false><<<dim3(8, 32), 256, 0, stream>>>(Obuf, Wob, out, 1024, 1024);
}

// Round 4
// 132.299 us; speedup vs baseline: 1.4378x; 1.0513x over previous
//
#include <hip/hip_runtime.h>
#include <hip/hip_bf16.h>
#include <stdint.h>

// Problem constants
#define B_  4
#define S_  1024
#define D_  1024
#define H_  16
#define HD_ 64

using f32x4  = __attribute__((ext_vector_type(4))) float;
using bf16x8 = __attribute__((ext_vector_type(8))) __bf16;
using bf16x4 = __attribute__((ext_vector_type(4))) __bf16;
using f32x4v = __attribute__((ext_vector_type(4))) float;

// ---------------------------------------------------------------------------
// global -> LDS direct load, 16B per lane. LDS dest must be wave-uniform base;
// HW writes lane i at base + i*16 (m104).
__device__ __forceinline__ void g2l16(const void* g, void* l) {
  using gp = const __attribute__((address_space(1))) unsigned int*;
  using lp = __attribute__((address_space(3))) unsigned int*;
  __builtin_amdgcn_global_load_lds((gp)(unsigned long long)g,
                                   (lp)(unsigned int)(unsigned long long)l,
                                   16, 0, 0);
}

// ---------------------------------------------------------------------------
// f32 -> bf16 conversion (vectorized, 4 elems/thread)
__global__ __launch_bounds__(256) void cvt_kernel(const float* __restrict__ in,
                                                  __bf16* __restrict__ out, int n) {
  int i = (blockIdx.x * 256 + threadIdx.x) * 4;
  if (i >= n) return;
  f32x4v v = *(const f32x4v*)(in + i);
  bf16x4 o;
  o[0] = (__bf16)v[0]; o[1] = (__bf16)v[1]; o[2] = (__bf16)v[2]; o[3] = (__bf16)v[3];
  *(bf16x4*)(out + i) = o;
}

// fused 4-weight cvt: blockIdx.y selects the weight (Wq,Wk,Wv -> Wqkv; Wo -> Wob)
__global__ __launch_bounds__(256)
void cvt4_kernel(const float* __restrict__ w0, const float* __restrict__ w1,
                 const float* __restrict__ w2, const float* __restrict__ w3,
                 __bf16* __restrict__ Wqkv, __bf16* __restrict__ Wob) {
  const int y = blockIdx.y;
  const float* src = (y == 0) ? w0 : (y == 1) ? w1 : (y == 2) ? w2 : w3;
  __bf16* dst = (y < 3) ? (Wqkv + (size_t)y * 1048576) : Wob;
  int i = (blockIdx.x * 256 + threadIdx.x) * 4;
  f32x4v v = *(const f32x4v*)(src + i);
  bf16x4 o;
  o[0] = (__bf16)v[0]; o[1] = (__bf16)v[1]; o[2] = (__bf16)v[2]; o[3] = (__bf16)v[3];
  *(bf16x4*)(dst + i) = o;
}

// num_masked per batch
__global__ __launch_bounds__(64) void nm_kernel(const unsigned char* __restrict__ m,
                                                int* __restrict__ nm) {
  int b = blockIdx.x, t = threadIdx.x;
  int s = 0;
  for (int i = t; i < S_; i += 64) s += (m[b * S_ + i] != 0) ? 1 : 0;
  #pragma unroll
  for (int k = 1; k < 64; k <<= 1) s += __shfl_xor(s, k);
  if (t == 0) nm[b] = s;
}

// ---------------------------------------------------------------------------
// NT GEMM: C[M,N] = A[M,K] * B[N,K]^T, bf16 in, f32 acc.
// 128x128 tile, BK=32, prefetch double-buffered LDS (one barrier per K-step),
// bank-conflict XOR swizzle (slot ^= (row>>1)&3) applied source-side + read-side.
template <bool OUT_BF16>
__global__ __launch_bounds__(256)
void gemm_nt(const __bf16* __restrict__ A, const __bf16* __restrict__ Bm,
             void* __restrict__ Cv, int N, int K) {
  __shared__ __bf16 sA[2][128 * 32];
  __shared__ __bf16 sB[2][128 * 32];
  const int tid = threadIdx.x;
  const int wv = tid >> 6, lane = tid & 63;
  const int row0 = blockIdx.y * 128, col0 = blockIdx.x * 128;
  const int wm = wv >> 1, wn = wv & 1;
  const int c0 = wv * 2, c1 = c0 + 1;
  const int srow = lane >> 2;                               // row within 16-row chunk
  const int scol = (((lane & 3) ^ ((lane >> 3) & 3))) * 8;  // swizzled source slot
  const __bf16* Ab = A + (size_t)(row0 + srow) * K + scol;
  const __bf16* Bb = Bm + (size_t)(col0 + srow) * K + scol;
  const int fr = lane & 15;
  const int fk = ((lane >> 4) ^ ((fr >> 1) & 3)) * 8;       // swizzled read col

  f32x4 acc[4][4] = {};

#define GSTAGE(buf, k0) do {                                              \
    g2l16(Ab + (size_t)(c0 * 16) * K + (k0), &sA[buf][c0 * 512]);         \
    g2l16(Ab + (size_t)(c1 * 16) * K + (k0), &sA[buf][c1 * 512]);         \
    g2l16(Bb + (size_t)(c0 * 16) * K + (k0), &sB[buf][c0 * 512]);         \
    g2l16(Bb + (size_t)(c1 * 16) * K + (k0), &sB[buf][c1 * 512]);         \
  } while (0)

  GSTAGE(0, 0);
  __syncthreads();
  int cur = 0;
  for (int k0 = 0; k0 < K; k0 += 32) {
    if (k0 + 32 < K) GSTAGE(cur ^ 1, k0 + 32);   // prefetch next tile

    bf16x8 af[4], bfr[4];
    #pragma unroll
    for (int m = 0; m < 4; ++m)
      af[m] = *(const bf16x8*)&sA[cur][(wm * 64 + m * 16 + fr) * 32 + fk];
    #pragma unroll
    for (int n = 0; n < 4; ++n)
      bfr[n] = *(const bf16x8*)&sB[cur][(wn * 64 + n * 16 + fr) * 32 + fk];

    #pragma unroll
    for (int m = 0; m < 4; ++m)
      #pragma unroll
      for (int n = 0; n < 4; ++n)
        acc[m][n] = __builtin_amdgcn_mfma_f32_16x16x32_bf16(af[m], bfr[n], acc[m][n], 0, 0, 0);

    __syncthreads();   // single barrier: drains prefetch vmcnt + protects buffers
    cur ^= 1;
  }
#undef GSTAGE

  const int g4 = (lane >> 4) * 4;
  if (OUT_BF16) {
    __bf16* C = (__bf16*)Cv;
    #pragma unroll
    for (int m = 0; m < 4; ++m)
      #pragma unroll
      for (int n = 0; n < 4; ++n)
        #pragma unroll
        for (int r = 0; r < 4; ++r)
          C[(size_t)(row0 + wm * 64 + m * 16 + g4 + r) * N + col0 + wn * 64 + n * 16 + fr] =
              (__bf16)acc[m][n][r];
  } else {
    float* C = (float*)Cv;
    #pragma unroll
    for (int m = 0; m < 4; ++m)
      #pragma unroll
      for (int n = 0; n < 4; ++n)
        #pragma unroll
        for (int r = 0; r < 4; ++r)
          C[(size_t)(row0 + wm * 64 + m * 16 + g4 + r) * N + col0 + wn * 64 + n * 16 + fr] =
              acc[m][n][r];
  }
}

// ---------------------------------------------------------------------------
// RoPE + RMSNorm + q per-dim scale. Block = one (b,s).
// q is pre-scaled by LOG2E^2/8 * softplus so attention scores are log2-domain.
__global__ __launch_bounds__(256)
void rope_rms(const __bf16* __restrict__ QKV, __bf16* __restrict__ Qr,
              __bf16* __restrict__ Kr, const float* __restrict__ qsc,
              const float* __restrict__ ksc, const float* __restrict__ pds,
              const int* __restrict__ nm) {
  const int bs = blockIdx.x;
  const int b = bs >> 10, s = bs & 1023;
  const int t = threadIdx.x;
  const bool isK = t >= 128;
  const int t2 = t & 127;
  const int h = t2 >> 3, j = t2 & 7;

  const __bf16* src = QKV + (size_t)bs * 3072 + (isK ? 1024 : 0) + h * 64 + j * 8;
  bf16x8 xv = *(const bf16x8*)src;
  float f[8], of[8];
  #pragma unroll
  for (int i = 0; i < 8; ++i) f[i] = (float)xv[i];

  const float pos = (float)s - (float)nm[b];
  #pragma unroll
  for (int i = 0; i < 8; ++i) {
    const float other = __shfl_xor(f[i], 4);
    const float frc = (float)((j & 3) * 8 + i) * (1.0f / 32.0f);
    const float ang = pos * exp2f(frc * -13.287712379549449f); // 1/10000^frc
    float sn, cs;
    sincosf(ang, &sn, &cs);
    of[i] = (j & 4) ? (f[i] * cs + other * sn)
                    : (f[i] * cs - other * sn);
  }

  float ss = 0.f;
  #pragma unroll
  for (int i = 0; i < 8; ++i) ss += of[i] * of[i];
  ss += __shfl_xor(ss, 1);
  ss += __shfl_xor(ss, 2);
  ss += __shfl_xor(ss, 4);
  const float rn = rsqrtf(ss * (1.0f / 64.0f) + 1e-6f);

  const float* sc = isK ? ksc : qsc;
  bf16x8 ov;
  #pragma unroll
  for (int i = 0; i < 8; ++i) {
    const int d = j * 8 + i;
    float v = of[i] * rn * sc[d];
    if (!isK) v *= 0.26017112262570096f * log1pf(expf(pds[d])); // LOG2E^2/8 * softplus
    ov[i] = (__bf16)v;
  }
  __bf16* dst = (isK ? Kr : Qr) + ((size_t)(b * H_ + h) * S_ + s) * HD_ + j * 8;
  *(bf16x8*)dst = ov;
}

// ---------------------------------------------------------------------------
// V transpose: QKV[:, 2048 + h*64 + d] -> Vt[b][h][d][s]
__global__ __launch_bounds__(256)
void vtrans(const __bf16* __restrict__ QKV, __bf16* __restrict__ Vt) {
  const int st = blockIdx.x, h = blockIdx.y, b = blockIdx.z;
  __shared__ __bf16 tile[64][72];
  const int t = threadIdx.x;
  const int r = t >> 2, q = t & 3;

  const __bf16* src = QKV + (size_t)(b * S_ + st * 64 + r) * 3072 + 2048 + h * 64 + q * 16;
  bf16x8 v0 = *(const bf16x8*)src;
  bf16x8 v1 = *(const bf16x8*)(src + 8);
  *(bf16x8*)&tile[r][q * 16] = v0;
  *(bf16x8*)&tile[r][q * 16 + 8] = v1;
  __syncthreads();

  __bf16 outv[16];
  #pragma unroll
  for (int i = 0; i < 16; ++i) outv[i] = tile[q * 16 + i][r];
  __bf16* dst = Vt + ((size_t)(b * H_ + h) * HD_ + r) * S_ + st * 64 + q * 16;
  *(bf16x8*)dst = *(bf16x8*)&outv[0];
  *(bf16x8*)(dst + 8) = *(bf16x8*)&outv[8];
}

// ---------------------------------------------------------------------------
// Flash attention v4: SWAPPED QK^T (compute S^T = K·Q^T) so each lane's 16
// acc values share one q-row -> softmax reduce = 15 in-reg fmax + 2 shfls
// (was 32 serial shfls/tile). PV computes O^T = V^T·P^T; P^T round-trips
// through wave-private LDS as 4 ds_write_b64 + 2 ds_read_b128 (XOR-swizzled).
// Block = 64 q rows (4 waves x 16), grid 1024, LDS 40960 -> 4 blocks/CU.
__global__ __launch_bounds__(256)
void attn_fwd(const __bf16* __restrict__ Qr, const __bf16* __restrict__ Kr,
              const __bf16* __restrict__ Vt, __bf16* __restrict__ Ob,
              const int* __restrict__ nm) {
  const int bid = blockIdx.x;
  const int qblk = 15 - (bid >> 6);      // longest blocks dispatch first
  const int bh = bid & 63;
  const int b = bh >> 4, h = bh & 15;
  const int q0 = qblk * 64;
  const int tid = threadIdx.x, wv = tid >> 6, lane = tid & 63;

  __shared__ __bf16 sK[2][64 * 64];
  __shared__ __bf16 sV[2][64 * 64];
  __shared__ unsigned int sP[4][16 * 32];   // per-wave P^T, [q=16][32 words]

  const size_t bhs = (size_t)(b * H_ + h);
  const __bf16* Qh = Qr + bhs * (S_ * HD_);
  const __bf16* Kh = Kr + bhs * (S_ * HD_);
  const __bf16* Vh = Vt + bhs * (HD_ * S_);

  const int fr = lane & 15, g = lane >> 4;
  const int qbase = q0 + wv * 16;
  const int q = qbase + fr;                 // this lane's q-row
  unsigned int* sPw = &sP[wv][0];
  const int swz = (fr & 7) << 2;            // sP word-XOR swizzle

  // Q as B-operand fragment (same memory pattern as before)
  bf16x8 qf[2];
  #pragma unroll
  for (int ks = 0; ks < 2; ++ks)
    qf[ks] = *(const bf16x8*)&Qh[(size_t)q * HD_ + ks * 32 + g * 8];

  f32x4 oacc[4] = {};                       // O^T: d = nd*16+g*4+r, col q=fr
  float mrun = -3e38f, lrun = 0.f;

  const int nmb = nm[b];
  const int srow = lane >> 3;
  const int ssw = ((lane & 7) ^ srow) * 8;  // inverse-swizzled source col
  const int c0 = wv * 2, c1 = c0 + 1;

#define ASTAGE(buf, kv) do {                                                    \
    g2l16(&Kh[(size_t)((kv) + c0 * 8 + srow) * HD_ + ssw], &sK[buf][c0 * 512]); \
    g2l16(&Kh[(size_t)((kv) + c1 * 8 + srow) * HD_ + ssw], &sK[buf][c1 * 512]); \
    g2l16(&Vh[(size_t)(c0 * 8 + srow) * S_ + (kv) + ssw], &sV[buf][c0 * 512]);  \
    g2l16(&Vh[(size_t)(c1 * 8 + srow) * S_ + (kv) + ssw], &sV[buf][c1 * 512]);  \
  } while (0)

  ASTAGE(0, 0);
  __syncthreads();
  int cur = 0;
  const int kvend = q0 + 64;

  for (int kv0 = 0; kv0 < kvend; kv0 += 64) {
    if (kv0 + 64 < kvend) ASTAGE(cur ^ 1, kv0 + 64);   // prefetch next tile

    // S^T = K Q^T : sacc[n][r] = S[q][kv0 + n*16 + g*4 + r]
    f32x4 sacc[4] = {};
    __builtin_amdgcn_s_setprio(1);
    #pragma unroll
    for (int n = 0; n < 4; ++n) {
      const int krow = n * 16 + fr;
      #pragma unroll
      for (int ks = 0; ks < 2; ++ks) {
        bf16x8 kf = *(const bf16x8*)&sK[cur][krow * 64 + ((ks * 32 + g * 8) ^ ((krow & 7) * 8))];
        sacc[n] = __builtin_amdgcn_mfma_f32_16x16x32_bf16(kf, qf[ks], sacc[n], 0, 0, 0);
      }
    }
    __builtin_amdgcn_s_setprio(0);

    // mask: valid iff q >= kv && kv >= nmb
    const bool fullv = (qbase >= kv0 + 63) && (kv0 >= nmb);
    if (!fullv) {
      #pragma unroll
      for (int n = 0; n < 4; ++n)
        #pragma unroll
        for (int r = 0; r < 4; ++r) {
          const int kv = kv0 + n * 16 + g * 4 + r;
          if (q < kv || kv < nmb) sacc[n][r] = -1e30f;
        }
    }

    // online softmax: all 16 in-lane values share q; cross-lane only over g
    float mx = sacc[0][0];
    #pragma unroll
    for (int n = 0; n < 4; ++n)
      #pragma unroll
      for (int r = 0; r < 4; ++r) mx = fmaxf(mx, sacc[n][r]);
    mx = fmaxf(mx, __shfl_xor(mx, 16));
    mx = fmaxf(mx, __shfl_xor(mx, 32));
    const float mnew = fmaxf(mrun, mx);
    const float scl = exp2f(mrun - mnew);
    float ls = 0.f;
    #pragma unroll
    for (int n = 0; n < 4; ++n)
      #pragma unroll
      for (int r = 0; r < 4; ++r) {
        const float p = exp2f(sacc[n][r] - mnew);
        sacc[n][r] = p;
        ls += p;
      }
    ls += __shfl_xor(ls, 16);
    ls += __shfl_xor(ls, 32);
    lrun = lrun * scl + ls;
    mrun = mnew;
    #pragma unroll
    for (int nd = 0; nd < 4; ++nd)
      #pragma unroll
      for (int r = 0; r < 4; ++r) oacc[nd][r] *= scl;

    // pack P^T -> wave-private LDS (bf16 pairs, b64 writes, XOR swizzle)
    #pragma unroll
    for (int n = 0; n < 4; ++n) {
      union { unsigned int u; __bf16 hh[2]; } p0, p1;
      p0.hh[0] = (__bf16)sacc[n][0]; p0.hh[1] = (__bf16)sacc[n][1];
      p1.hh[0] = (__bf16)sacc[n][2]; p1.hh[1] = (__bf16)sacc[n][3];
      const unsigned long long pu =
          (unsigned long long)p0.u | ((unsigned long long)p1.u << 32);
      *(unsigned long long*)&sPw[fr * 32 + ((n * 8 + g * 2) ^ swz)] = pu;
    }
    bf16x8 pf[2];
    #pragma unroll
    for (int ks = 0; ks < 2; ++ks)
      pf[ks] = *(const bf16x8*)&sPw[fr * 32 + ((ks * 16 + g * 4) ^ swz)];

    // O^T += V^T P^T
    __builtin_amdgcn_s_setprio(1);
    #pragma unroll
    for (int nd = 0; nd < 4; ++nd) {
      const int vrow = nd * 16 + fr;
      #pragma unroll
      for (int ks = 0; ks < 2; ++ks) {
        bf16x8 vf = *(const bf16x8*)&sV[cur][vrow * 64 + ((ks * 32 + g * 8) ^ ((vrow & 7) * 8))];
        oacc[nd] = __builtin_amdgcn_mfma_f32_16x16x32_bf16(vf, pf[ks], oacc[nd], 0, 0, 0);
      }
    }
    __builtin_amdgcn_s_setprio(0);

    __syncthreads();   // single barrier: drains prefetch + protects buffers
    cur ^= 1;
  }
#undef ASTAGE

  // normalize + write O row q (4 x 8B stores)
  const float inv = 1.0f / lrun;
  __bf16* orow = Ob + (size_t)(b * S_ + q) * D_ + h * HD_;
  #pragma unroll
  for (int nd = 0; nd < 4; ++nd) {
    bf16x4 ov;
    #pragma unroll
    for (int r = 0; r < 4; ++r) ov[r] = (__bf16)(oacc[nd][r] * inv);
    *(bf16x4*)&orow[nd * 16 + g * 4] = ov;
  }
}

// ---------------------------------------------------------------------------
extern "C" void kernel_launch(void* const* d_in, const int* in_sizes, int n_in,
                              void* d_out, int out_size, void* d_ws, size_t ws_size,
                              hipStream_t stream) {
  (void)in_sizes; (void)n_in; (void)out_size; (void)ws_size;
  const float* X  = (const float*)d_in[0];
  const unsigned char* pm = (const unsigned char*)d_in[1];
  const float* Wq = (const float*)d_in[2];
  const float* Wk = (const float*)d_in[3];
  const float* Wv = (const float*)d_in[4];
  const float* Wo = (const float*)d_in[5];
  const float* qs = (const float*)d_in[6];
  const float* ks = (const float*)d_in[7];
  const float* pd = (const float*)d_in[8];
  float* out = (float*)d_out;

  char* ws = (char*)d_ws;
  int*    nm   = (int*)ws;                               // [0, 256)
  __bf16* Wqkv = (__bf16*)(ws + 256);                    // 3072x1024
  __bf16* Wob  = (__bf16*)(ws + 256 + 6291456);          // 1024x1024
  __bf16* Xb   = (__bf16*)(ws + 8388864);                // 4096x1024
  __bf16* QKV  = (__bf16*)(ws + 16777472);               // 4096x3072
  __bf16* Krb  = (__bf16*)(ws + 41943296);               // [b,h,s,d]
  __bf16* Vtb  = (__bf16*)(ws + 50331904);               // [b,h,d,s]
  __bf16* Qrb  = Xb;                                     // alias
  __bf16* Obuf = QKV;                                    // alias

  cvt_kernel<<<4096, 256, 0, stream>>>(X, Xb, 4194304);
  cvt4_kernel<<<dim3(1024, 4), 256, 0, stream>>>(Wq, Wk, Wv, Wo, Wqkv, Wob);
  nm_kernel<<<4, 64, 0, stream>>>(pm, nm);

  // QKV = Xb @ Wqkv^T  (M=4096, N=3072, K=1024)
  gemm_nt<true><<<dim3(24, 32), 256, 0, stream>>>(Xb, Wqkv, QKV, 3072, 1024);

  rope_rms<<<4096, 256, 0, stream>>>(QKV, Qrb, Krb, qs, ks, pd, nm);
  vtrans<<<dim3(16, H_, B_), 256, 0, stream>>>(QKV, Vtb);

  attn_fwd<<<1024, 256, 0, stream>>>(Qrb, Krb, Vtb, Obuf, nm);

  // out = Obuf @ Wo^T  (M=4096, N=1024, K=1024)
  gemm_nt<false><<<dim3(8, 32), 256, 0, stream>>>(Obuf, Wob, out, 1024, 1024);
}